// Round 2
// baseline (455.999 us; speedup 1.0000x reference)
//
#include <hip/hip_runtime.h>
#include <hip/hip_bf16.h>
#include <stdint.h>

// CrossAttention (B=4, N=M=4096, C=512), fp32 in/out, bf16 MFMA internally.
// Round 2: 32x32x16 MFMA GEMM, XOR bank swizzle on LDS tiles, TM=256 for S.
//   Q  = rgb @ WqT^T (+bq)            [16384 x 512]       TM=128
//   K  = dep @ WkT^T (+bk)            [16384 x 512]       TM=128
//   Vt = WvT @ dep^T (+bv row)        per batch [512x4096] TM=128
//   S  = Q @ K^T * C^-0.5 -> bf16     per batch [4096x4096] TM=256
//   P  = softmax_rows(S) in-place
//   O  = P @ Vt^T -> fp32 d_out       per batch [4096x512] TM=128

typedef unsigned short u16;
typedef __attribute__((ext_vector_type(8))) short bf16x8;
typedef __attribute__((ext_vector_type(16))) float f32x16;
typedef __attribute__((ext_vector_type(4))) unsigned short u16x4;

#define GLD_LDS16(g, l)                                                        \
  __builtin_amdgcn_global_load_lds(                                            \
      (const __attribute__((address_space(1))) unsigned int*)(g),              \
      (__attribute__((address_space(3))) unsigned int*)(l), 16, 0, 0)

__device__ __forceinline__ u16 f2bf(float f) {  // RNE f32 -> bf16
  unsigned x = __float_as_uint(f);
  return (u16)((x + 0x7fffu + ((x >> 16) & 1u)) >> 16);
}

// ---------------------------------------------------------------------------
// GEMM: C[M,N] = A[M,K] * B[N,K]^T, bf16 in, fp32 acc, 32x32x16 MFMA.
// Block tile TM x 128, BK=32, 4 waves (2x2), wave tile (TM/2) x 64.
// LDS layout: [row][32 k-elems] (64 B rows), with the 4 16-B k-chunks of each
// row XOR-swizzled by (row&3) so fragment b128 reads hit all 32 banks.
// Staging via global_load_lds width=16; swizzle applied on the GLOBAL side
// (each lane loads chunk (lane&3)^(rowA&3)) since LDS dst is lane-contiguous.
// ---------------------------------------------------------------------------
template <int TM, int BIAS_MODE, bool OUT_F32, bool SCALE_EN>
__global__ __launch_bounds__(256, 2) void gemm32(
    const u16* __restrict__ A, const u16* __restrict__ Bm,
    const float* __restrict__ bias, void* __restrict__ Cv, int M, int N, int K,
    long long sAb, long long sBb, long long sCb, float scale) {
  constexpr int MSUB = TM / 64;  // 32-row m-subtiles per wave (2 or 4)
  const int bz = blockIdx.z;
  A += (size_t)bz * sAb;
  Bm += (size_t)bz * sBb;

  const int bm = blockIdx.y * TM;
  const int bn = blockIdx.x * 128;

  __shared__ u16 As[TM * 32];   // 8 or 16 KB
  __shared__ u16 Bs[128 * 32];  // 8 KB

  const int tid = threadIdx.x;
  const int wave = tid >> 6;
  const int lane = tid & 63;
  const int ln31 = lane & 31;  // MFMA 32x32: A.m / B.n / C.col
  const int half = lane >> 5;  // k = half*8 + j ; C.row += 4*half
  const int wr = wave >> 1;    // wave m-half
  const int wc = wave & 1;     // wave n-half

  const int rowA = lane >> 2;                      // row within 16-row chunk
  const int swz = ((lane & 3) ^ (rowA & 3)) * 8;   // swizzled k-elem offset

  f32x16 acc[MSUB][2] = {};

  for (int k0 = 0; k0 < K; k0 += 32) {
    __syncthreads();
#pragma unroll
    for (int r = 0; r < MSUB; ++r) {  // A: TM/16 chunks, MSUB per wave
      const int ch = wave * MSUB + r;
      GLD_LDS16(A + (size_t)(bm + ch * 16 + rowA) * K + k0 + swz,
                As + ch * 16 * 32);
    }
#pragma unroll
    for (int r = 0; r < 2; ++r) {  // B: 8 chunks, 2 per wave
      const int ch = wave * 2 + r;
      GLD_LDS16(Bm + (size_t)(bn + ch * 16 + rowA) * K + k0 + swz,
                Bs + ch * 16 * 32);
    }
    __syncthreads();

#pragma unroll
    for (int kc = 0; kc < 2; ++kc) {
      bf16x8 af[MSUB], bfv[2];
#pragma unroll
      for (int mt = 0; mt < MSUB; ++mt) {
        const int row = wr * (MSUB * 32) + mt * 32 + ln31;
        const int p = (kc * 2 + half) ^ (row & 3);  // un-swizzle
        af[mt] = *(const bf16x8*)&As[row * 32 + p * 8];
      }
#pragma unroll
      for (int nt = 0; nt < 2; ++nt) {
        const int row = wc * 64 + nt * 32 + ln31;
        const int p = (kc * 2 + half) ^ (row & 3);
        bfv[nt] = *(const bf16x8*)&Bs[row * 32 + p * 8];
      }
#pragma unroll
      for (int mt = 0; mt < MSUB; ++mt)
#pragma unroll
        for (int nt = 0; nt < 2; ++nt)
          acc[mt][nt] = __builtin_amdgcn_mfma_f32_32x32x16_bf16(
              af[mt], bfv[nt], acc[mt][nt], 0, 0, 0);
    }
  }

  // Epilogue. 32x32 C/D layout (m74/m101): col = lane&31,
  // row = (reg&3) + 8*(reg>>2) + 4*(lane>>5).
  const int crow0 = bm + wr * (MSUB * 32) + 4 * half;
  const int ccol0 = bn + wc * 64 + ln31;
#pragma unroll
  for (int mt = 0; mt < MSUB; ++mt) {
#pragma unroll
    for (int nt = 0; nt < 2; ++nt) {
      const int col = ccol0 + nt * 32;
#pragma unroll
      for (int r = 0; r < 16; ++r) {
        const int row = crow0 + mt * 32 + (r & 3) + 8 * (r >> 2);
        float v = acc[mt][nt][r];
        if constexpr (SCALE_EN) v *= scale;
        if constexpr (BIAS_MODE == 1) v += bias[col];
        if constexpr (BIAS_MODE == 2) v += bias[row];
        const size_t idx = (size_t)bz * (size_t)sCb + (size_t)row * N + col;
        if constexpr (OUT_F32)
          ((float*)Cv)[idx] = v;
        else
          ((u16*)Cv)[idx] = f2bf(v);
      }
    }
  }
}

// ---------------------------------------------------------------------------
// fp32 -> bf16 conversion for rgb + depth (two arrays in one launch).
// ---------------------------------------------------------------------------
__global__ __launch_bounds__(256) void cvt_pair(const float* __restrict__ x,
                                                const float* __restrict__ y,
                                                u16* __restrict__ ox,
                                                u16* __restrict__ oy, int n4) {
  const int i = blockIdx.x * 256 + threadIdx.x;
  if (i >= n4) return;
  const float4 a = ((const float4*)x)[i];
  const float4 b = ((const float4*)y)[i];
  u16x4 oa, ob;
  oa[0] = f2bf(a.x); oa[1] = f2bf(a.y); oa[2] = f2bf(a.z); oa[3] = f2bf(a.w);
  ob[0] = f2bf(b.x); ob[1] = f2bf(b.y); ob[2] = f2bf(b.z); ob[3] = f2bf(b.w);
  ((u16x4*)ox)[i] = oa;
  ((u16x4*)oy)[i] = ob;
}

// ---------------------------------------------------------------------------
// Transpose-convert 512x512 fp32 weight into bf16 WT[cout][cin].
// ---------------------------------------------------------------------------
__global__ __launch_bounds__(256) void wtrans_k(const float* __restrict__ W,
                                                u16* __restrict__ WT) {
  const int tr = blockIdx.y * 64;
  const int tc = blockIdx.x * 64;
  __shared__ float T[64][65];
  const int t = threadIdx.x;
  const int r0 = t >> 4;
  const int c0 = (t & 15) * 4;
#pragma unroll
  for (int rr = 0; rr < 4; ++rr) {
    const int row = rr * 16 + r0;
    const float4 w = *(const float4*)&W[(size_t)(tr + row) * 512 + tc + c0];
    T[row][c0 + 0] = w.x; T[row][c0 + 1] = w.y;
    T[row][c0 + 2] = w.z; T[row][c0 + 3] = w.w;
  }
  __syncthreads();
#pragma unroll
  for (int rr = 0; rr < 4; ++rr) {
    const int orow = rr * 16 + r0;
    u16x4 o;
#pragma unroll
    for (int j = 0; j < 4; ++j) o[j] = f2bf(T[c0 + j][orow]);
    *(u16x4*)&WT[(size_t)(tc + orow) * 512 + tr + c0] = o;
  }
}

// ---------------------------------------------------------------------------
// In-place row softmax over bf16 rows of length 4096. One block per row.
// ---------------------------------------------------------------------------
__global__ __launch_bounds__(256) void softmax_rows(u16* __restrict__ S,
                                                    int cols) {
  u16* p = S + (size_t)blockIdx.x * (size_t)cols;
  const int tid = threadIdx.x;
  const int lane = tid & 63;
  const int wave = tid >> 6;

  uint4 d[2];
  d[0] = ((const uint4*)p)[tid];
  d[1] = ((const uint4*)p)[tid + 256];

  float v[16];
#pragma unroll
  for (int i = 0; i < 2; ++i) {
    const unsigned* w = (const unsigned*)&d[i];
#pragma unroll
    for (int j = 0; j < 4; ++j) {
      v[i * 8 + j * 2 + 0] = __uint_as_float(w[j] << 16);
      v[i * 8 + j * 2 + 1] = __uint_as_float(w[j] & 0xffff0000u);
    }
  }

  float mx = -3.4e38f;
#pragma unroll
  for (int i = 0; i < 16; ++i) mx = fmaxf(mx, v[i]);
#pragma unroll
  for (int o = 32; o > 0; o >>= 1) mx = fmaxf(mx, __shfl_xor(mx, o, 64));

  __shared__ float red[4];
  if (lane == 0) red[wave] = mx;
  __syncthreads();
  mx = fmaxf(fmaxf(red[0], red[1]), fmaxf(red[2], red[3]));

  float s = 0.f;
#pragma unroll
  for (int i = 0; i < 16; ++i) {
    v[i] = __expf(v[i] - mx);
    s += v[i];
  }
#pragma unroll
  for (int o = 32; o > 0; o >>= 1) s += __shfl_xor(s, o, 64);
  __syncthreads();
  if (lane == 0) red[wave] = s;
  __syncthreads();
  s = (red[0] + red[1]) + (red[2] + red[3]);
  const float inv = 1.0f / s;

  uint4 o4[2];
#pragma unroll
  for (int i = 0; i < 2; ++i) {
    unsigned* w = (unsigned*)&o4[i];
#pragma unroll
    for (int j = 0; j < 4; ++j) {
      const unsigned lo = f2bf(v[i * 8 + j * 2 + 0] * inv);
      const unsigned hi = f2bf(v[i * 8 + j * 2 + 1] * inv);
      w[j] = lo | (hi << 16);
    }
  }
  ((uint4*)p)[tid] = o4[0];
  ((uint4*)p)[tid + 256] = o4[1];
}

// ---------------------------------------------------------------------------
extern "C" void kernel_launch(void* const* d_in, const int* in_sizes, int n_in,
                              void* d_out, int out_size, void* d_ws,
                              size_t ws_size, hipStream_t stream) {
  const float* rgb = (const float*)d_in[0];
  const float* dep = (const float*)d_in[1];
  const float* Wq = (const float*)d_in[2];
  const float* bq = (const float*)d_in[3];
  const float* Wk = (const float*)d_in[4];
  const float* bk = (const float*)d_in[5];
  const float* Wv = (const float*)d_in[6];
  const float* bv = (const float*)d_in[7];
  float* out = (float*)d_out;

  const int B = 4, N = 4096, M = 4096, C = 512;
  const size_t nBNC = (size_t)B * N * C;
  const float scale = 0.044194173824159216f;  // 512^-0.5

  char* ws = (char*)d_ws;
  size_t off = 0;
  auto carve = [&](size_t bytes) -> void* {
    void* p = ws + off;
    off += (bytes + 255) & ~(size_t)255;
    return p;
  };
  u16* rgb_bf = (u16*)carve(nBNC * 2);
  u16* dep_bf = (u16*)carve(nBNC * 2);
  u16* WqT = (u16*)carve((size_t)C * C * 2);
  u16* WkT = (u16*)carve((size_t)C * C * 2);
  u16* WvT = (u16*)carve((size_t)C * C * 2);
  u16* Qb = (u16*)carve(nBNC * 2);
  u16* Kb = (u16*)carve(nBNC * 2);
  u16* Vt = (u16*)carve(nBNC * 2);
  const size_t base = off;
  const size_t sFull = (size_t)B * N * M * 2;  // 134 MB
  const size_t sOne = (size_t)N * M * 2;       // 33.5 MB
  const bool full = ws_size >= base + sFull;
  u16* Sb = (u16*)carve(full ? sFull : sOne);

  // 0) dtype conversions
  cvt_pair<<<8192, 256, 0, stream>>>(rgb, dep, rgb_bf, dep_bf, (int)(nBNC / 4));
  wtrans_k<<<dim3(8, 8), 256, 0, stream>>>(Wq, WqT);
  wtrans_k<<<dim3(8, 8), 256, 0, stream>>>(Wk, WkT);
  wtrans_k<<<dim3(8, 8), 256, 0, stream>>>(Wv, WvT);

  const long long strQ = (long long)N * C;  // 2,097,152
  const long long strS = (long long)N * M;  // 16,777,216
  const long long strV = (long long)C * M;  // 2,097,152

  // 1) projections
  gemm32<128, 1, false, false><<<dim3(4, 128, 1), 256, 0, stream>>>(
      rgb_bf, WqT, bq, Qb, 16384, 512, 512, 0, 0, 0, 1.f);
  gemm32<128, 1, false, false><<<dim3(4, 128, 1), 256, 0, stream>>>(
      dep_bf, WkT, bk, Kb, 16384, 512, 512, 0, 0, 0, 1.f);
  gemm32<128, 2, false, false><<<dim3(32, 4, 4), 256, 0, stream>>>(
      WvT, dep_bf, bv, Vt, 512, 4096, 512, 0, strQ, strV, 1.f);

  if (full) {
    gemm32<256, 0, false, true><<<dim3(32, 16, 4), 256, 0, stream>>>(
        Qb, Kb, nullptr, Sb, 4096, 4096, 512, strQ, strQ, strS, scale);
    softmax_rows<<<16384, 256, 0, stream>>>(Sb, 4096);
    gemm32<128, 0, true, false><<<dim3(4, 32, 4), 256, 0, stream>>>(
        Sb, Vt, nullptr, out, 4096, 512, 4096, strS, strV, strQ, 1.f);
  } else {
    for (int b = 0; b < 4; ++b) {
      gemm32<256, 0, false, true><<<dim3(32, 16, 1), 256, 0, stream>>>(
          Qb + (size_t)b * strQ, Kb + (size_t)b * strQ, nullptr, Sb, 4096, 4096,
          512, 0, 0, 0, scale);
      softmax_rows<<<4096, 256, 0, stream>>>(Sb, 4096);
      gemm32<128, 0, true, false><<<dim3(4, 32, 1), 256, 0, stream>>>(
          Sb, Vt + (size_t)b * strV, nullptr, out + (size_t)b * strQ, 4096, 512,
          4096, 0, 0, 0, 1.f);
    }
  }
}

// Round 3
// 414.974 us; speedup vs baseline: 1.0989x; 1.0989x over previous
//
#include <hip/hip_runtime.h>
#include <hip/hip_bf16.h>
#include <stdint.h>

// CrossAttention (B=4, N=M=4096, C=512), fp32 in/out, bf16 MFMA internally.
// Round 3: fixed XOR bank swizzle g(r)=(r+(r>>2))&3; PV re-tiled 64x256 to
// halve S re-reads; launch_bounds(256,4) on low-VGPR configs.
//   Q  = rgb @ WqT^T (+bq)            [16384 x 512]        TM128xTN128
//   K  = dep @ WkT^T (+bk)            [16384 x 512]        TM128xTN128
//   Vt = WvT @ dep^T (+bv row)        per batch [512x4096] TM128xTN128
//   S  = Q @ K^T * C^-0.5 -> bf16     per batch [4096^2]   TM256xTN128
//   P  = softmax_rows(S) in-place
//   O  = P @ Vt^T -> fp32 d_out       per batch [4096x512] TM64xTN256

typedef unsigned short u16;
typedef __attribute__((ext_vector_type(8))) short bf16x8;
typedef __attribute__((ext_vector_type(16))) float f32x16;
typedef __attribute__((ext_vector_type(4))) unsigned short u16x4;

#define GLD_LDS16(g, l)                                                        \
  __builtin_amdgcn_global_load_lds(                                            \
      (const __attribute__((address_space(1))) unsigned int*)(g),              \
      (__attribute__((address_space(3))) unsigned int*)(l), 16, 0, 0)

__device__ __forceinline__ u16 f2bf(float f) {  // RNE f32 -> bf16
  unsigned x = __float_as_uint(f);
  return (u16)((x + 0x7fffu + ((x >> 16) & 1u)) >> 16);
}

// ---------------------------------------------------------------------------
// GEMM: C[M,N] = A[M,K] * B[N,K]^T, bf16 in, fp32 acc, 32x32x16 MFMA.
// Block tile TM x TN, BK=32, 4 waves arranged (4/WC) x WC, wave tile
// (TM*WC/4) x (TN/WC). LDS rows are 64 B; the 4 16-B k-chunks of row r are
// XOR-swizzled by g(r)=(r+(r>>2))&3 so b128 fragment reads cover all 32
// banks (bank-group (4(r&1)+p^g(r))%8 is bijective over 8 consecutive rows).
// g has period 16 and chunk/subtile bases are multiples of 16/32, so both
// the staging swizzle and the un-swizzle are per-lane constants.
// ---------------------------------------------------------------------------
template <int TM, int TN, int WC, int BIAS_MODE, bool OUT_F32, bool SCALE_EN,
          int MINW>
__global__ __launch_bounds__(256, MINW) void gemm32(
    const u16* __restrict__ A, const u16* __restrict__ Bm,
    const float* __restrict__ bias, void* __restrict__ Cv, int M, int N, int K,
    long long sAb, long long sBb, long long sCb, float scale) {
  constexpr int WROWS = TM * WC / 4;   // rows per wave
  constexpr int WCOLS = TN / WC;       // cols per wave
  constexpr int MSUB = WROWS / 32;
  constexpr int NSUB = WCOLS / 32;
  constexpr int CA = TM / 64;          // A 16-row chunks per wave
  constexpr int CB = TN / 64;          // B 16-row chunks per wave

  const int bz = blockIdx.z;
  A += (size_t)bz * sAb;
  Bm += (size_t)bz * sBb;

  const int bm = blockIdx.y * TM;
  const int bn = blockIdx.x * TN;

  __shared__ u16 As[TM * 32];
  __shared__ u16 Bs[TN * 32];

  const int tid = threadIdx.x;
  const int wave = tid >> 6;
  const int lane = tid & 63;
  const int ln31 = lane & 31;  // MFMA 32x32: A.m / B.n / C.col
  const int half = lane >> 5;  // k = half*8+j ; C.row += 4*half
  const int wr = wave / WC;
  const int wc = wave % WC;

  // Staging: 16 rows x 32 k per instruction; lane covers (row=lane>>2,
  // chunk=lane&3); source k-chunk is swizzled by g(row).
  const int rowA = lane >> 2;
  const int swz = ((lane & 3) ^ ((rowA + (rowA >> 2)) & 3)) * 8;
  // Fragment un-swizzle constant (row within subtile = ln31, base mult 32).
  const int gl = (ln31 + (ln31 >> 2)) & 3;

  f32x16 acc[MSUB][NSUB] = {};

  for (int k0 = 0; k0 < K; k0 += 32) {
    __syncthreads();
#pragma unroll
    for (int r = 0; r < CA; ++r) {
      const int ch = wave * CA + r;
      GLD_LDS16(A + (size_t)(bm + ch * 16 + rowA) * K + k0 + swz,
                As + ch * 16 * 32);
    }
#pragma unroll
    for (int r = 0; r < CB; ++r) {
      const int ch = wave * CB + r;
      GLD_LDS16(Bm + (size_t)(bn + ch * 16 + rowA) * K + k0 + swz,
                Bs + ch * 16 * 32);
    }
    __syncthreads();

#pragma unroll
    for (int kc = 0; kc < 2; ++kc) {
      const int p = ((kc * 2 + half) ^ gl) * 8;
      bf16x8 af[MSUB], bfv[NSUB];
#pragma unroll
      for (int mt = 0; mt < MSUB; ++mt)
        af[mt] = *(const bf16x8*)&As[(wr * WROWS + mt * 32 + ln31) * 32 + p];
#pragma unroll
      for (int nt = 0; nt < NSUB; ++nt)
        bfv[nt] = *(const bf16x8*)&Bs[(wc * WCOLS + nt * 32 + ln31) * 32 + p];
#pragma unroll
      for (int mt = 0; mt < MSUB; ++mt)
#pragma unroll
        for (int nt = 0; nt < NSUB; ++nt)
          acc[mt][nt] = __builtin_amdgcn_mfma_f32_32x32x16_bf16(
              af[mt], bfv[nt], acc[mt][nt], 0, 0, 0);
    }
  }

  // Epilogue. 32x32 C/D layout (m74/m101): col = lane&31,
  // row = (reg&3) + 8*(reg>>2) + 4*(lane>>5).
  const int crow0 = bm + wr * WROWS + 4 * half;
  const int ccol0 = bn + wc * WCOLS + ln31;
#pragma unroll
  for (int mt = 0; mt < MSUB; ++mt) {
#pragma unroll
    for (int nt = 0; nt < NSUB; ++nt) {
      const int col = ccol0 + nt * 32;
#pragma unroll
      for (int r = 0; r < 16; ++r) {
        const int row = crow0 + mt * 32 + (r & 3) + 8 * (r >> 2);
        float v = acc[mt][nt][r];
        if constexpr (SCALE_EN) v *= scale;
        if constexpr (BIAS_MODE == 1) v += bias[col];
        if constexpr (BIAS_MODE == 2) v += bias[row];
        const size_t idx = (size_t)bz * (size_t)sCb + (size_t)row * N + col;
        if constexpr (OUT_F32)
          ((float*)Cv)[idx] = v;
        else
          ((u16*)Cv)[idx] = f2bf(v);
      }
    }
  }
}

// ---------------------------------------------------------------------------
// fp32 -> bf16 conversion for rgb + depth (two arrays in one launch).
// ---------------------------------------------------------------------------
__global__ __launch_bounds__(256) void cvt_pair(const float* __restrict__ x,
                                                const float* __restrict__ y,
                                                u16* __restrict__ ox,
                                                u16* __restrict__ oy, int n4) {
  const int i = blockIdx.x * 256 + threadIdx.x;
  if (i >= n4) return;
  const float4 a = ((const float4*)x)[i];
  const float4 b = ((const float4*)y)[i];
  u16x4 oa, ob;
  oa[0] = f2bf(a.x); oa[1] = f2bf(a.y); oa[2] = f2bf(a.z); oa[3] = f2bf(a.w);
  ob[0] = f2bf(b.x); ob[1] = f2bf(b.y); ob[2] = f2bf(b.z); ob[3] = f2bf(b.w);
  ((u16x4*)ox)[i] = oa;
  ((u16x4*)oy)[i] = ob;
}

// ---------------------------------------------------------------------------
// Transpose-convert 512x512 fp32 weight into bf16 WT[cout][cin].
// ---------------------------------------------------------------------------
__global__ __launch_bounds__(256) void wtrans_k(const float* __restrict__ W,
                                                u16* __restrict__ WT) {
  const int tr = blockIdx.y * 64;
  const int tc = blockIdx.x * 64;
  __shared__ float T[64][65];
  const int t = threadIdx.x;
  const int r0 = t >> 4;
  const int c0 = (t & 15) * 4;
#pragma unroll
  for (int rr = 0; rr < 4; ++rr) {
    const int row = rr * 16 + r0;
    const float4 w = *(const float4*)&W[(size_t)(tr + row) * 512 + tc + c0];
    T[row][c0 + 0] = w.x; T[row][c0 + 1] = w.y;
    T[row][c0 + 2] = w.z; T[row][c0 + 3] = w.w;
  }
  __syncthreads();
#pragma unroll
  for (int rr = 0; rr < 4; ++rr) {
    const int orow = rr * 16 + r0;
    u16x4 o;
#pragma unroll
    for (int j = 0; j < 4; ++j) o[j] = f2bf(T[c0 + j][orow]);
    *(u16x4*)&WT[(size_t)(tc + orow) * 512 + tr + c0] = o;
  }
}

// ---------------------------------------------------------------------------
// In-place row softmax over bf16 rows of length 4096. One block per row.
// ---------------------------------------------------------------------------
__global__ __launch_bounds__(256) void softmax_rows(u16* __restrict__ S,
                                                    int cols) {
  u16* p = S + (size_t)blockIdx.x * (size_t)cols;
  const int tid = threadIdx.x;
  const int lane = tid & 63;
  const int wave = tid >> 6;

  uint4 d[2];
  d[0] = ((const uint4*)p)[tid];
  d[1] = ((const uint4*)p)[tid + 256];

  float v[16];
#pragma unroll
  for (int i = 0; i < 2; ++i) {
    const unsigned* w = (const unsigned*)&d[i];
#pragma unroll
    for (int j = 0; j < 4; ++j) {
      v[i * 8 + j * 2 + 0] = __uint_as_float(w[j] << 16);
      v[i * 8 + j * 2 + 1] = __uint_as_float(w[j] & 0xffff0000u);
    }
  }

  float mx = -3.4e38f;
#pragma unroll
  for (int i = 0; i < 16; ++i) mx = fmaxf(mx, v[i]);
#pragma unroll
  for (int o = 32; o > 0; o >>= 1) mx = fmaxf(mx, __shfl_xor(mx, o, 64));

  __shared__ float red[4];
  if (lane == 0) red[wave] = mx;
  __syncthreads();
  mx = fmaxf(fmaxf(red[0], red[1]), fmaxf(red[2], red[3]));

  float s = 0.f;
#pragma unroll
  for (int i = 0; i < 16; ++i) {
    v[i] = __expf(v[i] - mx);
    s += v[i];
  }
#pragma unroll
  for (int o = 32; o > 0; o >>= 1) s += __shfl_xor(s, o, 64);
  __syncthreads();
  if (lane == 0) red[wave] = s;
  __syncthreads();
  s = (red[0] + red[1]) + (red[2] + red[3]);
  const float inv = 1.0f / s;

  uint4 o4[2];
#pragma unroll
  for (int i = 0; i < 2; ++i) {
    unsigned* w = (unsigned*)&o4[i];
#pragma unroll
    for (int j = 0; j < 4; ++j) {
      const unsigned lo = f2bf(v[i * 8 + j * 2 + 0] * inv);
      const unsigned hi = f2bf(v[i * 8 + j * 2 + 1] * inv);
      w[j] = lo | (hi << 16);
    }
  }
  ((uint4*)p)[tid] = o4[0];
  ((uint4*)p)[tid + 256] = o4[1];
}

// ---------------------------------------------------------------------------
extern "C" void kernel_launch(void* const* d_in, const int* in_sizes, int n_in,
                              void* d_out, int out_size, void* d_ws,
                              size_t ws_size, hipStream_t stream) {
  const float* rgb = (const float*)d_in[0];
  const float* dep = (const float*)d_in[1];
  const float* Wq = (const float*)d_in[2];
  const float* bq = (const float*)d_in[3];
  const float* Wk = (const float*)d_in[4];
  const float* bk = (const float*)d_in[5];
  const float* Wv = (const float*)d_in[6];
  const float* bv = (const float*)d_in[7];
  float* out = (float*)d_out;

  const int B = 4, N = 4096, M = 4096, C = 512;
  const size_t nBNC = (size_t)B * N * C;
  const float scale = 0.044194173824159216f;  // 512^-0.5

  char* ws = (char*)d_ws;
  size_t off = 0;
  auto carve = [&](size_t bytes) -> void* {
    void* p = ws + off;
    off += (bytes + 255) & ~(size_t)255;
    return p;
  };
  u16* rgb_bf = (u16*)carve(nBNC * 2);
  u16* dep_bf = (u16*)carve(nBNC * 2);
  u16* WqT = (u16*)carve((size_t)C * C * 2);
  u16* WkT = (u16*)carve((size_t)C * C * 2);
  u16* WvT = (u16*)carve((size_t)C * C * 2);
  u16* Qb = (u16*)carve(nBNC * 2);
  u16* Kb = (u16*)carve(nBNC * 2);
  u16* Vt = (u16*)carve(nBNC * 2);
  const size_t base = off;
  const size_t sFull = (size_t)B * N * M * 2;  // 134 MB
  const size_t sOne = (size_t)N * M * 2;       // 33.5 MB
  const bool full = ws_size >= base + sFull;
  u16* Sb = (u16*)carve(full ? sFull : sOne);

  // 0) dtype conversions
  cvt_pair<<<8192, 256, 0, stream>>>(rgb, dep, rgb_bf, dep_bf, (int)(nBNC / 4));
  wtrans_k<<<dim3(8, 8), 256, 0, stream>>>(Wq, WqT);
  wtrans_k<<<dim3(8, 8), 256, 0, stream>>>(Wk, WkT);
  wtrans_k<<<dim3(8, 8), 256, 0, stream>>>(Wv, WvT);

  const long long strQ = (long long)N * C;  // 2,097,152
  const long long strS = (long long)N * M;  // 16,777,216
  const long long strV = (long long)C * M;  // 2,097,152

  // 1) projections
  gemm32<128, 128, 2, 1, false, false, 4><<<dim3(4, 128, 1), 256, 0, stream>>>(
      rgb_bf, WqT, bq, Qb, 16384, 512, 512, 0, 0, 0, 1.f);
  gemm32<128, 128, 2, 1, false, false, 4><<<dim3(4, 128, 1), 256, 0, stream>>>(
      dep_bf, WkT, bk, Kb, 16384, 512, 512, 0, 0, 0, 1.f);
  gemm32<128, 128, 2, 2, false, false, 4><<<dim3(32, 4, 4), 256, 0, stream>>>(
      WvT, dep_bf, bv, Vt, 512, 4096, 512, 0, strQ, strV, 1.f);

  if (full) {
    gemm32<256, 128, 2, 0, false, true, 2><<<dim3(32, 16, 4), 256, 0, stream>>>(
        Qb, Kb, nullptr, Sb, 4096, 4096, 512, strQ, strQ, strS, scale);
    softmax_rows<<<16384, 256, 0, stream>>>(Sb, 4096);
    gemm32<64, 256, 4, 0, true, false, 4><<<dim3(2, 64, 4), 256, 0, stream>>>(
        Sb, Vt, nullptr, out, 4096, 512, 4096, strS, strV, strQ, 1.f);
  } else {
    for (int b = 0; b < 4; ++b) {
      gemm32<256, 128, 2, 0, false, true, 2>
          <<<dim3(32, 16, 1), 256, 0, stream>>>(Qb + (size_t)b * strQ,
                                                Kb + (size_t)b * strQ, nullptr,
                                                Sb, 4096, 4096, 512, 0, 0, 0,
                                                scale);
      softmax_rows<<<4096, 256, 0, stream>>>(Sb, 4096);
      gemm32<64, 256, 4, 0, true, false, 4><<<dim3(2, 64, 1), 256, 0, stream>>>(
          Sb, Vt + (size_t)b * strV, nullptr, out + (size_t)b * strQ, 4096, 512,
          4096, 0, 0, 0, 1.f);
    }
  }
}